// Round 19
// baseline (125.290 us; speedup 1.0000x reference)
//
#include <hip/hip_runtime.h>
#include <stdint.h>

#define NGRP 16384   // B
#define DIM  300
#define ODIM 64
#define KPAD 320     // 300 padded to 10*32
#define WPAD 328     // Wt LDS row pad: +4 banks mod 32 -> 2-way alias (free)
#define JC   32      // j-chunks for score kernel

// exp(dot/tau) = exp(2*dot) = 2^(dot * 2*log2(e))
#define EXP2SCALE 2.8853900817779268f

typedef __attribute__((ext_vector_type(8))) short bf16x8;
typedef __attribute__((ext_vector_type(4))) float f32x4;

static __device__ __forceinline__ unsigned short f2bf(float f) {
  union { float f; unsigned u; } x; x.f = f;
  unsigned r = x.u + 0x7fffu + ((x.u >> 16) & 1u);   // RNE
  return (unsigned short)(r >> 16);
}

// 8x f32 -> 8x bf16 via packed converts (RNE)
static __device__ __forceinline__ bf16x8 pack8(float4 a, float4 b) {
  union { bf16x8 v; uint32_t u[4]; } r;
  asm("v_cvt_pk_bf16_f32 %0, %1, %2" : "=v"(r.u[0]) : "v"(a.x), "v"(a.y));
  asm("v_cvt_pk_bf16_f32 %0, %1, %2" : "=v"(r.u[1]) : "v"(a.z), "v"(a.w));
  asm("v_cvt_pk_bf16_f32 %0, %1, %2" : "=v"(r.u[2]) : "v"(b.x), "v"(b.y));
  asm("v_cvt_pk_bf16_f32 %0, %1, %2" : "=v"(r.u[3]) : "v"(b.z), "v"(b.w));
  return r.v;
}

static __device__ __forceinline__ float red32(float v) {
  v += __shfl_xor(v, 1); v += __shfl_xor(v, 2); v += __shfl_xor(v, 4);
  v += __shfl_xor(v, 8); v += __shfl_xor(v, 16);
  return v;
}

// W [300][64] fp32 -> Wt [64][320] bf16, zero-padded past k=300
__global__ __launch_bounds__(256) void prep_wt(const float* __restrict__ W,
                                               unsigned short* __restrict__ wt) {
  int o = blockIdx.x * 256 + threadIdx.x;      // over 64*320
  if (o >= ODIM * KPAD) return;
  int n = o / KPAD, k = o % KPAD;
  float v = (k < DIM) ? W[(size_t)k * ODIM + n] : 0.f;
  wt[o] = f2bf(v);
}

// Branch: the 170-VGPR boundary experiment. r15/r18 sit at 172-176 VGPR
// = 2 waves/SIMD (3-wave boundary is <=170); r18 proved LDS alone isn't
// binding. This version crosses BOTH caps: (1) pool/anchor aliased onto
// wlds (LDS 42KB, 3 blocks/CU by LDS), (2) bl[4] folded to one LDS base +
// compile-time ds offsets (-3 addr VGPRs), (3) #pragma unroll 3 on the
// K-loop to cap the a-load hoist window (the main VGPR consumer).
// Target: VGPR <=170 -> 3 blocks/CU (+50% waves). NO clamps (4 strikes).
template <bool POS>
__global__ __launch_bounds__(256) void branch_mfma(
    const float* __restrict__ feat, const float* __restrict__ ew,
    const unsigned short* __restrict__ wt, const float* __restrict__ bias,
    const float* __restrict__ prelu_a, const float* __restrict__ Ws,
    const float* __restrict__ bs,
    unsigned short* __restrict__ emb,      // [NGRP][64] bf16 (anchor: prescaled)
    float* __restrict__ pos_dot)           // [NGRP] (POS only)
{
  __shared__ unsigned short wlds[ODIM * WPAD];   // 41984 B; reused after K-loop
  float* lds_pool   = (float*)wlds;              // [32][65] = 8320 B
  float* lds_anchor = (float*)wlds + 32 * 65;    // [32][65] (16640 B < 41984)
  const int tid = threadIdx.x, wid = tid >> 6, lane = tid & 63;
  const int lm = lane & 15, lh = lane >> 4;
  const int wrow = blockIdx.x * 128 + wid * 32;

  // stage Wt: 64 rows x 40 16B-chunks = 2560 chunks, 10 per thread
  #pragma unroll
  for (int k = 0; k < 10; ++k) {
    const int c = tid + k * 256;
    const int row = c / 40, off = (c % 40) * 8;
    *(bf16x8*)&wlds[row * WPAD + off] = *(const bf16x8*)(wt + row * KPAD + off);
  }

  const float* ap[2];
  #pragma unroll
  for (int rt = 0; rt < 2; ++rt)
    ap[rt] = feat + (size_t)(wrow + rt * 16 + lm) * DIM + lh * 8;
  // single LDS base; b-tile ct at compile-time offset ct*16*WPAD (+k0)
  const unsigned short* blbase = &wlds[lm * WPAD + lh * 8];

  f32x4 acc[2][4];
  #pragma unroll
  for (int rt = 0; rt < 2; ++rt)
    #pragma unroll
    for (int ct = 0; ct < 4; ++ct) acc[rt][ct] = (f32x4){0.f, 0.f, 0.f, 0.f};

  __syncthreads();

  #pragma unroll 3
  for (int step = 0; step < 9; ++step) {     // k0 = 0..256, all in-bounds
    const int k0 = step * 32;
    bf16x8 a[2], b[4];
    #pragma unroll
    for (int ct = 0; ct < 4; ++ct)
      b[ct] = *(const bf16x8*)(blbase + ct * 16 * WPAD + k0);
    #pragma unroll
    for (int rt = 0; rt < 2; ++rt) {
      const float* p = ap[rt] + k0;
      a[rt] = pack8(*(const float4*)p, *(const float4*)(p + 4));
    }
    #pragma unroll
    for (int rt = 0; rt < 2; ++rt)
      #pragma unroll
      for (int ct = 0; ct < 4; ++ct)
        acc[rt][ct] = __builtin_amdgcn_mfma_f32_16x16x32_bf16(a[rt], b[ct], acc[rt][ct], 0, 0, 0);
  }
  { // k0 = 288: cols 288..299 valid, 300..319 zero (Wt zero-padded)
    bf16x8 a[2], b[4];
    #pragma unroll
    for (int ct = 0; ct < 4; ++ct)
      b[ct] = *(const bf16x8*)(blbase + ct * 16 * WPAD + 288);
    #pragma unroll
    for (int rt = 0; rt < 2; ++rt) {
      float4 f0 = {0.f, 0.f, 0.f, 0.f}, f1 = {0.f, 0.f, 0.f, 0.f};
      const float* p = ap[rt] + 288;
      if (lh == 0) { f0 = *(const float4*)p; f1 = *(const float4*)(p + 4); }
      else if (lh == 1) { f0 = *(const float4*)p; }   // cols 296..299
      a[rt] = pack8(f0, f1);
    }
    #pragma unroll
    for (int rt = 0; rt < 2; ++rt)
      #pragma unroll
      for (int ct = 0; ct < 4; ++ct)
        acc[rt][ct] = __builtin_amdgcn_mfma_f32_16x16x32_bf16(a[rt], b[ct], acc[rt][ct], 0, 0, 0);
  }

  __syncthreads();   // all waves done READING wlds before pool/anchor overwrite

  // Phase 1: C/D layout row=(lh*4+r) => each lane's 4 regs = one full group.
  const float pa = prelu_a[0];
  float bc[4];
  #pragma unroll
  for (int ct = 0; ct < 4; ++ct) bc[ct] = bias[ct * 16 + lm];

  #pragma unroll
  for (int rt = 0; rt < 2; ++rt) {
    const int gblk = wid * 8 + rt * 4 + lh;                  // 0..31
    const size_t grp = (size_t)blockIdx.x * 32 + gblk;
    const float* e = ew + grp * 16;
    float w1[4], w2[4], w3[4];
    #pragma unroll
    for (int j = 0; j < 4; ++j) { w1[j] = e[4 + j]; w2[j] = e[8 + j]; w3[j] = e[12 + j]; }
    #pragma unroll
    for (int ct = 0; ct < 4; ++ct) {
      const int c = ct * 16 + lm;
      const float x0 = acc[rt][ct][0], x1 = acc[rt][ct][1];
      const float x2 = acc[rt][ct][2], x3 = acc[rt][ct][3];
      float pool = 0.f;
      #pragma unroll
      for (int j = 0; j < 4; ++j) {
        float h = fmaf(w1[j], x1, fmaf(w2[j], x2, w3[j] * x3)) + bc[ct];
        h = (h >= 0.f) ? h : pa * h;
        pool += h;
      }
      lds_pool[gblk * 65 + c] = pool * 0.25f;
      if (POS) {
        float av = x0 + bc[ct];
        av = (av >= 0.f) ? av : pa * av;
        lds_anchor[gblk * 65 + c] = av;
      }
    }
  }
  __syncthreads();

  // Phase 2: y = pool @ Ws + bs, 4 groups x 2 cols per thread
  const int c2 = (tid & 31) * 2;
  const int g0 = (tid >> 5) * 4;                             // group set base (0..28)
  float y[4][2];
  { const float b0 = bs[c2], b1 = bs[c2 + 1];
    #pragma unroll
    for (int j = 0; j < 4; ++j) { y[j][0] = b0; y[j][1] = b1; } }
  for (int o = 0; o < ODIM; o += 4) {
    float4 pv[4];
    #pragma unroll
    for (int j = 0; j < 4; ++j) pv[j] = *(const float4*)&lds_pool[(g0 + j) * 65 + o];
    #pragma unroll
    for (int u = 0; u < 4; ++u) {
      float2 w = *(const float2*)(Ws + (size_t)(o + u) * ODIM + c2);
      #pragma unroll
      for (int j = 0; j < 4; ++j) {
        const float p = (&pv[j].x)[u];
        y[j][0] = fmaf(p, w.x, y[j][0]);
        y[j][1] = fmaf(p, w.y, y[j][1]);
      }
    }
  }
  #pragma unroll
  for (int j = 0; j < 4; ++j) {
    const size_t grp = (size_t)blockIdx.x * 32 + g0 + j;
    float s = red32(y[j][0] * y[j][0] + y[j][1] * y[j][1]);
    const float inv = 1.f / fmaxf(sqrtf(s), 1e-12f);
    if (POS) {
      const float a0 = lds_anchor[(g0 + j) * 65 + c2];
      const float a1 = lds_anchor[(g0 + j) * 65 + c2 + 1];
      float s2 = red32(a0 * a0 + a1 * a1);
      const float inv2 = 1.f / fmaxf(sqrtf(s2), 1e-12f);
      float dot = red32(a0 * y[j][0] + a1 * y[j][1]) * inv * inv2;
      if ((tid & 31) == 0) pos_dot[grp] = dot;
      const float sc = inv2 * EXP2SCALE;   // prescale: score kernel does exp2(dot) directly
      ushort2 st; st.x = f2bf(a0 * sc); st.y = f2bf(a1 * sc);
      *(ushort2*)(emb + grp * ODIM + c2) = st;
    } else {
      ushort2 st; st.x = f2bf(y[j][0] * inv); st.y = f2bf(y[j][1] * inv);
      *(ushort2*)(emb + grp * ODIM + c2) = st;
    }
  }
}

// Score config B3 (r12/r15, byte-identical — proven best at 59us, VGPR 68):
// 9KB single-buffer stage, 2 staging regs, 2 barriers/iter. Occupancy
// experiments exhausted (r8/r13/r14/r16/r17 all null or worse). Do not touch.
__global__ __launch_bounds__(256) void score_kernel(
    const unsigned short* __restrict__ pa, const unsigned short* __restrict__ npl,
    float* __restrict__ partial)  // [JC][NGRP]
{
  __shared__ unsigned short kv[4 * 16 * 72];   // 4 tiles x 16 rows x 72 elems = 9216 B
  const int tid = threadIdx.x;
  const int wid = tid >> 6, lane = tid & 63;
  const int lm = lane & 15, lh = lane >> 4;
  const int rwb = blockIdx.x * 256 + wid * 64;
  const int jbase = blockIdx.y * (NGRP / JC);   // 512

  bf16x8 af[4][2];
  #pragma unroll
  for (int mt = 0; mt < 4; ++mt) {
    const unsigned short* ap = pa + (size_t)(rwb + mt * 16 + lm) * ODIM + lh * 8;
    af[mt][0] = *(const bf16x8*)(ap);
    af[mt][1] = *(const bf16x8*)(ap + 32);
  }

  float s[4][4];
  #pragma unroll
  for (int mt = 0; mt < 4; ++mt)
    #pragma unroll
    for (int r = 0; r < 4; ++r) s[mt][r] = 0.f;

  // j-chunk is a contiguous 512x64 block: chunk g (16B) = global bytes g*16.
  const unsigned short* src = npl + (size_t)jbase * ODIM;
  const int g1 = tid + 256;
  const int d0 = (tid >> 7) * 1152 + ((tid >> 3) & 15) * 72 + (tid & 7) * 8;
  const int d1 = (g1  >> 7) * 1152 + ((g1  >> 3) & 15) * 72 + (g1  & 7) * 8;
  const int ro = lm * 72 + lh * 8;             // per-lane read offset within a tile

  bf16x8 ld0 = *(const bf16x8*)(src + tid * 8);
  bf16x8 ld1 = *(const bf16x8*)(src + g1 * 8);

  for (int it = 0; it < 8; ++it) {             // 8 buffers x 4 tiles = 32 tiles
    *(bf16x8*)&kv[d0] = ld0;
    *(bf16x8*)&kv[d1] = ld1;
    __syncthreads();
    if (it < 7) {                              // prefetch next 8KB buffer
      const unsigned short* ns = src + (it + 1) * 4096;
      ld0 = *(const bf16x8*)(ns + tid * 8);
      ld1 = *(const bf16x8*)(ns + g1 * 8);
    }
    #pragma unroll
    for (int tt = 0; tt < 4; ++tt) {
      const unsigned short* kp = &kv[tt * 1152 + ro];
      bf16x8 b0 = *(const bf16x8*)(kp);
      bf16x8 b1 = *(const bf16x8*)(kp + 32);
      #pragma unroll
      for (int mt = 0; mt < 4; ++mt) {
        f32x4 d = {0.f, 0.f, 0.f, 0.f};
        d = __builtin_amdgcn_mfma_f32_16x16x32_bf16(af[mt][0], b0, d, 0, 0, 0);
        d = __builtin_amdgcn_mfma_f32_16x16x32_bf16(af[mt][1], b1, d, 0, 0, 0);
        #pragma unroll
        for (int r = 0; r < 4; ++r) s[mt][r] += __builtin_amdgcn_exp2f(d[r]);
      }
    }
    __syncthreads();
  }

  #pragma unroll
  for (int mt = 0; mt < 4; ++mt)
    #pragma unroll
    for (int r = 0; r < 4; ++r) {
      float v = s[mt][r];
      v += __shfl_xor(v, 1); v += __shfl_xor(v, 2);
      v += __shfl_xor(v, 4); v += __shfl_xor(v, 8);
      s[mt][r] = v;
    }

  if (lm == 0) {
    float* pr = partial + (size_t)blockIdx.y * NGRP + rwb + lh * 4;
    #pragma unroll
    for (int mt = 0; mt < 4; ++mt)
      #pragma unroll
      for (int r = 0; r < 4; ++r)
        pr[mt * 16 + r] = s[mt][r];
  }
}

__global__ __launch_bounds__(256) void final_kernel(
    const float* __restrict__ pos_dot, const float* __restrict__ partial,
    float* __restrict__ out)
{
  const int i = blockIdx.x * 256 + threadIdx.x;
  float na = 0.f;
  #pragma unroll
  for (int c = 0; c < JC; ++c) na += partial[(size_t)c * NGRP + i];
  float ps = expf(pos_dot[i] * 2.0f);              // exp(dot / tau)
  out[i]             = -logf(ps / (na + 1e-5f));   // loss_pool
  out[NGRP + i]      = ps;                         // pos_score (BETA=0)
  out[2 * NGRP + i]  = na * (1.0f / (float)NGRP);  // neg_score
}

extern "C" void kernel_launch(void* const* d_in, const int* in_sizes, int n_in,
                              void* d_out, int out_size, void* d_ws, size_t ws_size,
                              hipStream_t stream) {
  const float* pos_feat = (const float*)d_in[0];
  const float* pos_w    = (const float*)d_in[3];
  const float* neg_feat = (const float*)d_in[4];
  const float* neg_w    = (const float*)d_in[7];
  const float* W        = (const float*)d_in[12];
  const float* bias     = (const float*)d_in[13];
  const float* prelu_a  = (const float*)d_in[14];
  const float* Ws       = (const float*)d_in[15];
  const float* bs       = (const float*)d_in[16];
  // aug_*, src/dst, Wg/bg, Wa1/ba1, Wa2/ba2: dead code (BETA=0, fixed graph)

  char* ws = (char*)d_ws;
  unsigned short* pa_bf   = (unsigned short*)(ws);                          // 2 MB
  unsigned short* np_bf   = (unsigned short*)(ws + (2u << 20));             // 2 MB
  float*          partial = (float*)(ws + (4u << 20));                      // 2 MB
  float*          pos_dot = (float*)(ws + (6u << 20));                      // 64 KB
  unsigned short* wt      = (unsigned short*)(ws + (6u << 20) + (64u << 10)); // 40 KB

  prep_wt<<<(ODIM * KPAD + 255) / 256, 256, 0, stream>>>(W, wt);
  branch_mfma<true ><<<NGRP / 32, 256, 0, stream>>>(pos_feat, pos_w, wt, bias,
                                                    prelu_a, Ws, bs, pa_bf, pos_dot);
  branch_mfma<false><<<NGRP / 32, 256, 0, stream>>>(neg_feat, neg_w, wt, bias,
                                                    prelu_a, Ws, bs, np_bf, nullptr);
  score_kernel<<<dim3(NGRP / 256, JC), 256, 0, stream>>>(pa_bf, np_bf, partial);
  final_kernel<<<NGRP / 256, 256, 0, stream>>>(pos_dot, partial, (float*)d_out);
}

// Round 20
// 118.939 us; speedup vs baseline: 1.0534x; 1.0534x over previous
//
#include <hip/hip_runtime.h>
#include <stdint.h>

#define NGRP 16384   // B
#define DIM  300
#define ODIM 64
#define KPAD 320     // 300 padded to 10*32
#define WPAD 328     // Wt LDS row pad: +4 banks mod 32 -> 2-way alias (free)
#define JC   32      // j-chunks for score kernel

// exp(dot/tau) = exp(2*dot) = 2^(dot * 2*log2(e))
#define EXP2SCALE 2.8853900817779268f

typedef __attribute__((ext_vector_type(8))) short bf16x8;
typedef __attribute__((ext_vector_type(4))) float f32x4;

static __device__ __forceinline__ unsigned short f2bf(float f) {
  union { float f; unsigned u; } x; x.f = f;
  unsigned r = x.u + 0x7fffu + ((x.u >> 16) & 1u);   // RNE
  return (unsigned short)(r >> 16);
}

// 8x f32 -> 8x bf16 via packed converts (RNE)
static __device__ __forceinline__ bf16x8 pack8(float4 a, float4 b) {
  union { bf16x8 v; uint32_t u[4]; } r;
  asm("v_cvt_pk_bf16_f32 %0, %1, %2" : "=v"(r.u[0]) : "v"(a.x), "v"(a.y));
  asm("v_cvt_pk_bf16_f32 %0, %1, %2" : "=v"(r.u[1]) : "v"(a.z), "v"(a.w));
  asm("v_cvt_pk_bf16_f32 %0, %1, %2" : "=v"(r.u[2]) : "v"(b.x), "v"(b.y));
  asm("v_cvt_pk_bf16_f32 %0, %1, %2" : "=v"(r.u[3]) : "v"(b.z), "v"(b.w));
  return r.v;
}

static __device__ __forceinline__ float red32(float v) {
  v += __shfl_xor(v, 1); v += __shfl_xor(v, 2); v += __shfl_xor(v, 4);
  v += __shfl_xor(v, 8); v += __shfl_xor(v, 16);
  return v;
}

// W [300][64] fp32 -> Wt [64][320] bf16, zero-padded past k=300
__global__ __launch_bounds__(256) void prep_wt(const float* __restrict__ W,
                                               unsigned short* __restrict__ wt) {
  int o = blockIdx.x * 256 + threadIdx.x;      // over 64*320
  if (o >= ODIM * KPAD) return;
  int n = o / KPAD, k = o % KPAD;
  float v = (k < DIM) ? W[(size_t)k * ODIM + n] : 0.f;
  wt[o] = f2bf(v);
}

// Branch: 1-row-tile/wave + Wt-in-LDS + pool/anchor alias. Mechanism:
// 1-tile measured VGPR 120 with GLOBAL Wt (r12); LDS Wt removes the bp
// pointers + b hoisting -> est ~100-110 VGPR -> 4-5 waves/SIMD by regs.
// Alias -> LDS 42KB -> 3 blocks/CU. First config where NEITHER cap binds
// at 2: ~12 waves/CU vs r15's 8. Grid 1024/branch. NO clamps (4 strikes).
template <bool POS>
__global__ __launch_bounds__(256) void branch_mfma(
    const float* __restrict__ feat, const float* __restrict__ ew,
    const unsigned short* __restrict__ wt, const float* __restrict__ bias,
    const float* __restrict__ prelu_a, const float* __restrict__ Ws,
    const float* __restrict__ bs,
    unsigned short* __restrict__ emb,      // [NGRP][64] bf16 (anchor: prescaled)
    float* __restrict__ pos_dot)           // [NGRP] (POS only)
{
  __shared__ unsigned short wlds[ODIM * WPAD];   // 41984 B; reused after K-loop
  float* lds_pool   = (float*)wlds;              // [16][65] = 4160 B
  float* lds_anchor = (float*)wlds + 16 * 65;    // [16][65] (8320 B < 41984)
  const int tid = threadIdx.x, wid = tid >> 6, lane = tid & 63;
  const int lm = lane & 15, lh = lane >> 4;
  const int wrow = blockIdx.x * 64 + wid * 16;

  // stage Wt: 64 rows x 40 16B-chunks = 2560 chunks, 10 per thread
  #pragma unroll
  for (int k = 0; k < 10; ++k) {
    const int c = tid + k * 256;
    const int row = c / 40, off = (c % 40) * 8;
    *(bf16x8*)&wlds[row * WPAD + off] = *(const bf16x8*)(wt + row * KPAD + off);
  }

  const float* ap = feat + (size_t)(wrow + lm) * DIM + lh * 8;
  const unsigned short* blbase = &wlds[lm * WPAD + lh * 8];

  f32x4 acc[4];
  #pragma unroll
  for (int ct = 0; ct < 4; ++ct) acc[ct] = (f32x4){0.f, 0.f, 0.f, 0.f};

  __syncthreads();

  #pragma unroll
  for (int step = 0; step < 9; ++step) {     // k0 = 0..256, all in-bounds
    const int k0 = step * 32;
    bf16x8 b[4];
    #pragma unroll
    for (int ct = 0; ct < 4; ++ct)
      b[ct] = *(const bf16x8*)(blbase + ct * 16 * WPAD + k0);
    const float* p = ap + k0;
    bf16x8 a = pack8(*(const float4*)p, *(const float4*)(p + 4));
    #pragma unroll
    for (int ct = 0; ct < 4; ++ct)
      acc[ct] = __builtin_amdgcn_mfma_f32_16x16x32_bf16(a, b[ct], acc[ct], 0, 0, 0);
  }
  { // k0 = 288: cols 288..299 valid, 300..319 zero (Wt zero-padded)
    bf16x8 b[4];
    #pragma unroll
    for (int ct = 0; ct < 4; ++ct)
      b[ct] = *(const bf16x8*)(blbase + ct * 16 * WPAD + 288);
    float4 f0 = {0.f, 0.f, 0.f, 0.f}, f1 = {0.f, 0.f, 0.f, 0.f};
    const float* p = ap + 288;
    if (lh == 0) { f0 = *(const float4*)p; f1 = *(const float4*)(p + 4); }
    else if (lh == 1) { f0 = *(const float4*)p; }   // cols 296..299
    bf16x8 a = pack8(f0, f1);
    #pragma unroll
    for (int ct = 0; ct < 4; ++ct)
      acc[ct] = __builtin_amdgcn_mfma_f32_16x16x32_bf16(a, b[ct], acc[ct], 0, 0, 0);
  }

  __syncthreads();   // all waves done READING wlds before pool/anchor overwrite

  // Phase 1: C/D layout row=(lh*4+r) => each lane's 4 regs = one full group.
  const float pa = prelu_a[0];
  float bc[4];
  #pragma unroll
  for (int ct = 0; ct < 4; ++ct) bc[ct] = bias[ct * 16 + lm];

  {
    const int gblk = wid * 4 + lh;                           // 0..15
    const size_t grp = (size_t)blockIdx.x * 16 + gblk;
    const float* e = ew + grp * 16;
    float w1[4], w2[4], w3[4];
    #pragma unroll
    for (int j = 0; j < 4; ++j) { w1[j] = e[4 + j]; w2[j] = e[8 + j]; w3[j] = e[12 + j]; }
    #pragma unroll
    for (int ct = 0; ct < 4; ++ct) {
      const int c = ct * 16 + lm;
      const float x0 = acc[ct][0], x1 = acc[ct][1];
      const float x2 = acc[ct][2], x3 = acc[ct][3];
      float pool = 0.f;
      #pragma unroll
      for (int j = 0; j < 4; ++j) {
        float h = fmaf(w1[j], x1, fmaf(w2[j], x2, w3[j] * x3)) + bc[ct];
        h = (h >= 0.f) ? h : pa * h;
        pool += h;
      }
      lds_pool[gblk * 65 + c] = pool * 0.25f;
      if (POS) {
        float av = x0 + bc[ct];
        av = (av >= 0.f) ? av : pa * av;
        lds_anchor[gblk * 65 + c] = av;
      }
    }
  }
  __syncthreads();

  // Phase 2: y = pool @ Ws + bs, 2 groups x 2 cols per thread
  const int c2 = (tid & 31) * 2;
  const int g0 = (tid >> 5) * 2;                             // group base (0..14)
  float y[2][2];
  { const float b0 = bs[c2], b1 = bs[c2 + 1];
    #pragma unroll
    for (int j = 0; j < 2; ++j) { y[j][0] = b0; y[j][1] = b1; } }
  for (int o = 0; o < ODIM; o += 4) {
    float4 pv[2];
    #pragma unroll
    for (int j = 0; j < 2; ++j) pv[j] = *(const float4*)&lds_pool[(g0 + j) * 65 + o];
    #pragma unroll
    for (int u = 0; u < 4; ++u) {
      float2 w = *(const float2*)(Ws + (size_t)(o + u) * ODIM + c2);
      #pragma unroll
      for (int j = 0; j < 2; ++j) {
        const float p = (&pv[j].x)[u];
        y[j][0] = fmaf(p, w.x, y[j][0]);
        y[j][1] = fmaf(p, w.y, y[j][1]);
      }
    }
  }
  #pragma unroll
  for (int j = 0; j < 2; ++j) {
    const size_t grp = (size_t)blockIdx.x * 16 + g0 + j;
    float s = red32(y[j][0] * y[j][0] + y[j][1] * y[j][1]);
    const float inv = 1.f / fmaxf(sqrtf(s), 1e-12f);
    if (POS) {
      const float a0 = lds_anchor[(g0 + j) * 65 + c2];
      const float a1 = lds_anchor[(g0 + j) * 65 + c2 + 1];
      float s2 = red32(a0 * a0 + a1 * a1);
      const float inv2 = 1.f / fmaxf(sqrtf(s2), 1e-12f);
      float dot = red32(a0 * y[j][0] + a1 * y[j][1]) * inv * inv2;
      if ((tid & 31) == 0) pos_dot[grp] = dot;
      const float sc = inv2 * EXP2SCALE;   // prescale: score kernel does exp2(dot) directly
      ushort2 st; st.x = f2bf(a0 * sc); st.y = f2bf(a1 * sc);
      *(ushort2*)(emb + grp * ODIM + c2) = st;
    } else {
      ushort2 st; st.x = f2bf(y[j][0] * inv); st.y = f2bf(y[j][1] * inv);
      *(ushort2*)(emb + grp * ODIM + c2) = st;
    }
  }
}

// Score config B3 (r12/r15, byte-identical — proven best at 59us, VGPR 68):
// 9KB single-buffer stage, 2 staging regs, 2 barriers/iter. Occupancy
// experiments exhausted (r8/r13/r14/r16/r17 all null or worse). Do not touch.
__global__ __launch_bounds__(256) void score_kernel(
    const unsigned short* __restrict__ pa, const unsigned short* __restrict__ npl,
    float* __restrict__ partial)  // [JC][NGRP]
{
  __shared__ unsigned short kv[4 * 16 * 72];   // 4 tiles x 16 rows x 72 elems = 9216 B
  const int tid = threadIdx.x;
  const int wid = tid >> 6, lane = tid & 63;
  const int lm = lane & 15, lh = lane >> 4;
  const int rwb = blockIdx.x * 256 + wid * 64;
  const int jbase = blockIdx.y * (NGRP / JC);   // 512

  bf16x8 af[4][2];
  #pragma unroll
  for (int mt = 0; mt < 4; ++mt) {
    const unsigned short* ap = pa + (size_t)(rwb + mt * 16 + lm) * ODIM + lh * 8;
    af[mt][0] = *(const bf16x8*)(ap);
    af[mt][1] = *(const bf16x8*)(ap + 32);
  }

  float s[4][4];
  #pragma unroll
  for (int mt = 0; mt < 4; ++mt)
    #pragma unroll
    for (int r = 0; r < 4; ++r) s[mt][r] = 0.f;

  // j-chunk is a contiguous 512x64 block: chunk g (16B) = global bytes g*16.
  const unsigned short* src = npl + (size_t)jbase * ODIM;
  const int g1 = tid + 256;
  const int d0 = (tid >> 7) * 1152 + ((tid >> 3) & 15) * 72 + (tid & 7) * 8;
  const int d1 = (g1  >> 7) * 1152 + ((g1  >> 3) & 15) * 72 + (g1  & 7) * 8;
  const int ro = lm * 72 + lh * 8;             // per-lane read offset within a tile

  bf16x8 ld0 = *(const bf16x8*)(src + tid * 8);
  bf16x8 ld1 = *(const bf16x8*)(src + g1 * 8);

  for (int it = 0; it < 8; ++it) {             // 8 buffers x 4 tiles = 32 tiles
    *(bf16x8*)&kv[d0] = ld0;
    *(bf16x8*)&kv[d1] = ld1;
    __syncthreads();
    if (it < 7) {                              // prefetch next 8KB buffer
      const unsigned short* ns = src + (it + 1) * 4096;
      ld0 = *(const bf16x8*)(ns + tid * 8);
      ld1 = *(const bf16x8*)(ns + g1 * 8);
    }
    #pragma unroll
    for (int tt = 0; tt < 4; ++tt) {
      const unsigned short* kp = &kv[tt * 1152 + ro];
      bf16x8 b0 = *(const bf16x8*)(kp);
      bf16x8 b1 = *(const bf16x8*)(kp + 32);
      #pragma unroll
      for (int mt = 0; mt < 4; ++mt) {
        f32x4 d = {0.f, 0.f, 0.f, 0.f};
        d = __builtin_amdgcn_mfma_f32_16x16x32_bf16(af[mt][0], b0, d, 0, 0, 0);
        d = __builtin_amdgcn_mfma_f32_16x16x32_bf16(af[mt][1], b1, d, 0, 0, 0);
        #pragma unroll
        for (int r = 0; r < 4; ++r) s[mt][r] += __builtin_amdgcn_exp2f(d[r]);
      }
    }
    __syncthreads();
  }

  #pragma unroll
  for (int mt = 0; mt < 4; ++mt)
    #pragma unroll
    for (int r = 0; r < 4; ++r) {
      float v = s[mt][r];
      v += __shfl_xor(v, 1); v += __shfl_xor(v, 2);
      v += __shfl_xor(v, 4); v += __shfl_xor(v, 8);
      s[mt][r] = v;
    }

  if (lm == 0) {
    float* pr = partial + (size_t)blockIdx.y * NGRP + rwb + lh * 4;
    #pragma unroll
    for (int mt = 0; mt < 4; ++mt)
      #pragma unroll
      for (int r = 0; r < 4; ++r)
        pr[mt * 16 + r] = s[mt][r];
  }
}

__global__ __launch_bounds__(256) void final_kernel(
    const float* __restrict__ pos_dot, const float* __restrict__ partial,
    float* __restrict__ out)
{
  const int i = blockIdx.x * 256 + threadIdx.x;
  float na = 0.f;
  #pragma unroll
  for (int c = 0; c < JC; ++c) na += partial[(size_t)c * NGRP + i];
  float ps = expf(pos_dot[i] * 2.0f);              // exp(dot / tau)
  out[i]             = -logf(ps / (na + 1e-5f));   // loss_pool
  out[NGRP + i]      = ps;                         // pos_score (BETA=0)
  out[2 * NGRP + i]  = na * (1.0f / (float)NGRP);  // neg_score
}

extern "C" void kernel_launch(void* const* d_in, const int* in_sizes, int n_in,
                              void* d_out, int out_size, void* d_ws, size_t ws_size,
                              hipStream_t stream) {
  const float* pos_feat = (const float*)d_in[0];
  const float* pos_w    = (const float*)d_in[3];
  const float* neg_feat = (const float*)d_in[4];
  const float* neg_w    = (const float*)d_in[7];
  const float* W        = (const float*)d_in[12];
  const float* bias     = (const float*)d_in[13];
  const float* prelu_a  = (const float*)d_in[14];
  const float* Ws       = (const float*)d_in[15];
  const float* bs       = (const float*)d_in[16];
  // aug_*, src/dst, Wg/bg, Wa1/ba1, Wa2/ba2: dead code (BETA=0, fixed graph)

  char* ws = (char*)d_ws;
  unsigned short* pa_bf   = (unsigned short*)(ws);                          // 2 MB
  unsigned short* np_bf   = (unsigned short*)(ws + (2u << 20));             // 2 MB
  float*          partial = (float*)(ws + (4u << 20));                      // 2 MB
  float*          pos_dot = (float*)(ws + (6u << 20));                      // 64 KB
  unsigned short* wt      = (unsigned short*)(ws + (6u << 20) + (64u << 10)); // 40 KB

  prep_wt<<<(ODIM * KPAD + 255) / 256, 256, 0, stream>>>(W, wt);
  branch_mfma<true ><<<NGRP / 16, 256, 0, stream>>>(pos_feat, pos_w, wt, bias,
                                                    prelu_a, Ws, bs, pa_bf, pos_dot);
  branch_mfma<false><<<NGRP / 16, 256, 0, stream>>>(neg_feat, neg_w, wt, bias,
                                                    prelu_a, Ws, bs, np_bf, nullptr);
  score_kernel<<<dim3(NGRP / 256, JC), 256, 0, stream>>>(pa_bf, np_bf, partial);
  final_kernel<<<NGRP / 256, 256, 0, stream>>>(pos_dot, partial, (float*)d_out);
}

// Round 21
// 108.648 us; speedup vs baseline: 1.1532x; 1.0947x over previous
//
#include <hip/hip_runtime.h>
#include <stdint.h>

#define NGRP 16384   // B
#define DIM  300
#define ODIM 64
#define KPAD 320     // 300 padded to 10*32
#define WPAD 328     // Wt LDS row pad: +4 banks mod 32 -> 2-way alias (free)
#define JC   32      // j-chunks for score kernel

// exp(dot/tau) = exp(2*dot) = 2^(dot * 2*log2(e))
#define EXP2SCALE 2.8853900817779268f

typedef __attribute__((ext_vector_type(8))) short bf16x8;
typedef __attribute__((ext_vector_type(4))) float f32x4;

static __device__ __forceinline__ unsigned short f2bf(float f) {
  union { float f; unsigned u; } x; x.f = f;
  unsigned r = x.u + 0x7fffu + ((x.u >> 16) & 1u);   // RNE
  return (unsigned short)(r >> 16);
}

// 8x f32 -> 8x bf16 via packed converts (RNE)
static __device__ __forceinline__ bf16x8 pack8(float4 a, float4 b) {
  union { bf16x8 v; uint32_t u[4]; } r;
  asm("v_cvt_pk_bf16_f32 %0, %1, %2" : "=v"(r.u[0]) : "v"(a.x), "v"(a.y));
  asm("v_cvt_pk_bf16_f32 %0, %1, %2" : "=v"(r.u[1]) : "v"(a.z), "v"(a.w));
  asm("v_cvt_pk_bf16_f32 %0, %1, %2" : "=v"(r.u[2]) : "v"(b.x), "v"(b.y));
  asm("v_cvt_pk_bf16_f32 %0, %1, %2" : "=v"(r.u[3]) : "v"(b.z), "v"(b.w));
  return r.v;
}

static __device__ __forceinline__ float red32(float v) {
  v += __shfl_xor(v, 1); v += __shfl_xor(v, 2); v += __shfl_xor(v, 4);
  v += __shfl_xor(v, 8); v += __shfl_xor(v, 16);
  return v;
}

// W [300][64] fp32 -> Wt [64][320] bf16, zero-padded past k=300
__global__ __launch_bounds__(256) void prep_wt(const float* __restrict__ W,
                                               unsigned short* __restrict__ wt) {
  int o = blockIdx.x * 256 + threadIdx.x;      // over 64*320
  if (o >= ODIM * KPAD) return;
  int n = o / KPAD, k = o % KPAD;
  float v = (k < DIM) ? W[(size_t)k * ODIM + n] : 0.f;
  wt[o] = f2bf(v);
}

// Branch — r15 version byte-exact (best measured config, total 108.7us).
// 2 row-tiles/wave, 512 blocks/branch, Wt staged in LDS (ds_read_b128
// b-fragments, 2-way alias free), SEPARATE pool/anchor LDS arrays, NO
// launch_bounds clamps. All perturbations tried and rejected:
// alias (r18), unroll-cap/addr-fold (r19), 1-row-tile (r20), clamps (r16).
template <bool POS>
__global__ __launch_bounds__(256) void branch_mfma(
    const float* __restrict__ feat, const float* __restrict__ ew,
    const unsigned short* __restrict__ wt, const float* __restrict__ bias,
    const float* __restrict__ prelu_a, const float* __restrict__ Ws,
    const float* __restrict__ bs,
    unsigned short* __restrict__ emb,      // [NGRP][64] bf16 (anchor: prescaled)
    float* __restrict__ pos_dot)           // [NGRP] (POS only)
{
  __shared__ unsigned short wlds[ODIM * WPAD];   // 41984 B
  __shared__ float lds_pool[32][65];
  __shared__ float lds_anchor[32][65];
  const int tid = threadIdx.x, wid = tid >> 6, lane = tid & 63;
  const int lm = lane & 15, lh = lane >> 4;
  const int wrow = blockIdx.x * 128 + wid * 32;

  // stage Wt: 64 rows x 40 16B-chunks = 2560 chunks, 10 per thread
  #pragma unroll
  for (int k = 0; k < 10; ++k) {
    const int c = tid + k * 256;
    const int row = c / 40, off = (c % 40) * 8;
    *(bf16x8*)&wlds[row * WPAD + off] = *(const bf16x8*)(wt + row * KPAD + off);
  }

  const float* ap[2];
  #pragma unroll
  for (int rt = 0; rt < 2; ++rt)
    ap[rt] = feat + (size_t)(wrow + rt * 16 + lm) * DIM + lh * 8;
  const unsigned short* bl[4];
  #pragma unroll
  for (int ct = 0; ct < 4; ++ct)
    bl[ct] = &wlds[(ct * 16 + lm) * WPAD + lh * 8];

  f32x4 acc[2][4];
  #pragma unroll
  for (int rt = 0; rt < 2; ++rt)
    #pragma unroll
    for (int ct = 0; ct < 4; ++ct) acc[rt][ct] = (f32x4){0.f, 0.f, 0.f, 0.f};

  __syncthreads();

  #pragma unroll
  for (int step = 0; step < 9; ++step) {     // k0 = 0..256, all in-bounds
    const int k0 = step * 32;
    bf16x8 a[2], b[4];
    #pragma unroll
    for (int ct = 0; ct < 4; ++ct) b[ct] = *(const bf16x8*)(bl[ct] + k0);
    #pragma unroll
    for (int rt = 0; rt < 2; ++rt) {
      const float* p = ap[rt] + k0;
      a[rt] = pack8(*(const float4*)p, *(const float4*)(p + 4));
    }
    #pragma unroll
    for (int rt = 0; rt < 2; ++rt)
      #pragma unroll
      for (int ct = 0; ct < 4; ++ct)
        acc[rt][ct] = __builtin_amdgcn_mfma_f32_16x16x32_bf16(a[rt], b[ct], acc[rt][ct], 0, 0, 0);
  }
  { // k0 = 288: cols 288..299 valid, 300..319 zero (Wt zero-padded)
    bf16x8 a[2], b[4];
    #pragma unroll
    for (int ct = 0; ct < 4; ++ct) b[ct] = *(const bf16x8*)(bl[ct] + 288);
    #pragma unroll
    for (int rt = 0; rt < 2; ++rt) {
      float4 f0 = {0.f, 0.f, 0.f, 0.f}, f1 = {0.f, 0.f, 0.f, 0.f};
      const float* p = ap[rt] + 288;
      if (lh == 0) { f0 = *(const float4*)p; f1 = *(const float4*)(p + 4); }
      else if (lh == 1) { f0 = *(const float4*)p; }   // cols 296..299
      a[rt] = pack8(f0, f1);
    }
    #pragma unroll
    for (int rt = 0; rt < 2; ++rt)
      #pragma unroll
      for (int ct = 0; ct < 4; ++ct)
        acc[rt][ct] = __builtin_amdgcn_mfma_f32_16x16x32_bf16(a[rt], b[ct], acc[rt][ct], 0, 0, 0);
  }

  // Phase 1: C/D layout row=(lh*4+r) => each lane's 4 regs = one full group.
  const float pa = prelu_a[0];
  float bc[4];
  #pragma unroll
  for (int ct = 0; ct < 4; ++ct) bc[ct] = bias[ct * 16 + lm];

  #pragma unroll
  for (int rt = 0; rt < 2; ++rt) {
    const int gblk = wid * 8 + rt * 4 + lh;                  // 0..31
    const size_t grp = (size_t)blockIdx.x * 32 + gblk;
    const float* e = ew + grp * 16;
    float w1[4], w2[4], w3[4];
    #pragma unroll
    for (int j = 0; j < 4; ++j) { w1[j] = e[4 + j]; w2[j] = e[8 + j]; w3[j] = e[12 + j]; }
    #pragma unroll
    for (int ct = 0; ct < 4; ++ct) {
      const int c = ct * 16 + lm;
      const float x0 = acc[rt][ct][0], x1 = acc[rt][ct][1];
      const float x2 = acc[rt][ct][2], x3 = acc[rt][ct][3];
      float pool = 0.f;
      #pragma unroll
      for (int j = 0; j < 4; ++j) {
        float h = fmaf(w1[j], x1, fmaf(w2[j], x2, w3[j] * x3)) + bc[ct];
        h = (h >= 0.f) ? h : pa * h;
        pool += h;
      }
      lds_pool[gblk][c] = pool * 0.25f;
      if (POS) {
        float av = x0 + bc[ct];
        av = (av >= 0.f) ? av : pa * av;
        lds_anchor[gblk][c] = av;
      }
    }
  }
  __syncthreads();

  // Phase 2: y = pool @ Ws + bs, 4 groups x 2 cols per thread
  const int c2 = (tid & 31) * 2;
  const int g0 = (tid >> 5) * 4;                             // group set base (0..28)
  float y[4][2];
  { const float b0 = bs[c2], b1 = bs[c2 + 1];
    #pragma unroll
    for (int j = 0; j < 4; ++j) { y[j][0] = b0; y[j][1] = b1; } }
  for (int o = 0; o < ODIM; o += 4) {
    float4 pv[4];
    #pragma unroll
    for (int j = 0; j < 4; ++j) pv[j] = *(const float4*)&lds_pool[g0 + j][o];
    #pragma unroll
    for (int u = 0; u < 4; ++u) {
      float2 w = *(const float2*)(Ws + (size_t)(o + u) * ODIM + c2);
      #pragma unroll
      for (int j = 0; j < 4; ++j) {
        const float p = (&pv[j].x)[u];
        y[j][0] = fmaf(p, w.x, y[j][0]);
        y[j][1] = fmaf(p, w.y, y[j][1]);
      }
    }
  }
  #pragma unroll
  for (int j = 0; j < 4; ++j) {
    const size_t grp = (size_t)blockIdx.x * 32 + g0 + j;
    float s = red32(y[j][0] * y[j][0] + y[j][1] * y[j][1]);
    const float inv = 1.f / fmaxf(sqrtf(s), 1e-12f);
    if (POS) {
      const float a0 = lds_anchor[g0 + j][c2], a1 = lds_anchor[g0 + j][c2 + 1];
      float s2 = red32(a0 * a0 + a1 * a1);
      const float inv2 = 1.f / fmaxf(sqrtf(s2), 1e-12f);
      float dot = red32(a0 * y[j][0] + a1 * y[j][1]) * inv * inv2;
      if ((tid & 31) == 0) pos_dot[grp] = dot;
      const float sc = inv2 * EXP2SCALE;   // prescale: score kernel does exp2(dot) directly
      ushort2 st; st.x = f2bf(a0 * sc); st.y = f2bf(a1 * sc);
      *(ushort2*)(emb + grp * ODIM + c2) = st;
    } else {
      ushort2 st; st.x = f2bf(y[j][0] * inv); st.y = f2bf(y[j][1] * inv);
      *(ushort2*)(emb + grp * ODIM + c2) = st;
    }
  }
}

// Score config B3 (r12/r15, byte-identical — proven best at 59us, VGPR 68):
// 9KB single-buffer stage, 2 staging regs, 2 barriers/iter. All variants
// rejected: ping-pong (r11), mt=8 (r13), 16KB (r14), clamp (r16), mt=2 (r17).
__global__ __launch_bounds__(256) void score_kernel(
    const unsigned short* __restrict__ pa, const unsigned short* __restrict__ npl,
    float* __restrict__ partial)  // [JC][NGRP]
{
  __shared__ unsigned short kv[4 * 16 * 72];   // 4 tiles x 16 rows x 72 elems = 9216 B
  const int tid = threadIdx.x;
  const int wid = tid >> 6, lane = tid & 63;
  const int lm = lane & 15, lh = lane >> 4;
  const int rwb = blockIdx.x * 256 + wid * 64;
  const int jbase = blockIdx.y * (NGRP / JC);   // 512

  bf16x8 af[4][2];
  #pragma unroll
  for (int mt = 0; mt < 4; ++mt) {
    const unsigned short* ap = pa + (size_t)(rwb + mt * 16 + lm) * ODIM + lh * 8;
    af[mt][0] = *(const bf16x8*)(ap);
    af[mt][1] = *(const bf16x8*)(ap + 32);
  }

  float s[4][4];
  #pragma unroll
  for (int mt = 0; mt < 4; ++mt)
    #pragma unroll
    for (int r = 0; r < 4; ++r) s[mt][r] = 0.f;

  // j-chunk is a contiguous 512x64 block: chunk g (16B) = global bytes g*16.
  const unsigned short* src = npl + (size_t)jbase * ODIM;
  const int g1 = tid + 256;
  const int d0 = (tid >> 7) * 1152 + ((tid >> 3) & 15) * 72 + (tid & 7) * 8;
  const int d1 = (g1  >> 7) * 1152 + ((g1  >> 3) & 15) * 72 + (g1  & 7) * 8;
  const int ro = lm * 72 + lh * 8;             // per-lane read offset within a tile

  bf16x8 ld0 = *(const bf16x8*)(src + tid * 8);
  bf16x8 ld1 = *(const bf16x8*)(src + g1 * 8);

  for (int it = 0; it < 8; ++it) {             // 8 buffers x 4 tiles = 32 tiles
    *(bf16x8*)&kv[d0] = ld0;
    *(bf16x8*)&kv[d1] = ld1;
    __syncthreads();
    if (it < 7) {                              // prefetch next 8KB buffer
      const unsigned short* ns = src + (it + 1) * 4096;
      ld0 = *(const bf16x8*)(ns + tid * 8);
      ld1 = *(const bf16x8*)(ns + g1 * 8);
    }
    #pragma unroll
    for (int tt = 0; tt < 4; ++tt) {
      const unsigned short* kp = &kv[tt * 1152 + ro];
      bf16x8 b0 = *(const bf16x8*)(kp);
      bf16x8 b1 = *(const bf16x8*)(kp + 32);
      #pragma unroll
      for (int mt = 0; mt < 4; ++mt) {
        f32x4 d = {0.f, 0.f, 0.f, 0.f};
        d = __builtin_amdgcn_mfma_f32_16x16x32_bf16(af[mt][0], b0, d, 0, 0, 0);
        d = __builtin_amdgcn_mfma_f32_16x16x32_bf16(af[mt][1], b1, d, 0, 0, 0);
        #pragma unroll
        for (int r = 0; r < 4; ++r) s[mt][r] += __builtin_amdgcn_exp2f(d[r]);
      }
    }
    __syncthreads();
  }

  #pragma unroll
  for (int mt = 0; mt < 4; ++mt)
    #pragma unroll
    for (int r = 0; r < 4; ++r) {
      float v = s[mt][r];
      v += __shfl_xor(v, 1); v += __shfl_xor(v, 2);
      v += __shfl_xor(v, 4); v += __shfl_xor(v, 8);
      s[mt][r] = v;
    }

  if (lm == 0) {
    float* pr = partial + (size_t)blockIdx.y * NGRP + rwb + lh * 4;
    #pragma unroll
    for (int mt = 0; mt < 4; ++mt)
      #pragma unroll
      for (int r = 0; r < 4; ++r)
        pr[mt * 16 + r] = s[mt][r];
  }
}

__global__ __launch_bounds__(256) void final_kernel(
    const float* __restrict__ pos_dot, const float* __restrict__ partial,
    float* __restrict__ out)
{
  const int i = blockIdx.x * 256 + threadIdx.x;
  float na = 0.f;
  #pragma unroll
  for (int c = 0; c < JC; ++c) na += partial[(size_t)c * NGRP + i];
  float ps = expf(pos_dot[i] * 2.0f);              // exp(dot / tau)
  out[i]             = -logf(ps / (na + 1e-5f));   // loss_pool
  out[NGRP + i]      = ps;                         // pos_score (BETA=0)
  out[2 * NGRP + i]  = na * (1.0f / (float)NGRP);  // neg_score
}

extern "C" void kernel_launch(void* const* d_in, const int* in_sizes, int n_in,
                              void* d_out, int out_size, void* d_ws, size_t ws_size,
                              hipStream_t stream) {
  const float* pos_feat = (const float*)d_in[0];
  const float* pos_w    = (const float*)d_in[3];
  const float* neg_feat = (const float*)d_in[4];
  const float* neg_w    = (const float*)d_in[7];
  const float* W        = (const float*)d_in[12];
  const float* bias     = (const float*)d_in[13];
  const float* prelu_a  = (const float*)d_in[14];
  const float* Ws       = (const float*)d_in[15];
  const float* bs       = (const float*)d_in[16];
  // aug_*, src/dst, Wg/bg, Wa1/ba1, Wa2/ba2: dead code (BETA=0, fixed graph)

  char* ws = (char*)d_ws;
  unsigned short* pa_bf   = (unsigned short*)(ws);                          // 2 MB
  unsigned short* np_bf   = (unsigned short*)(ws + (2u << 20));             // 2 MB
  float*          partial = (float*)(ws + (4u << 20));                      // 2 MB
  float*          pos_dot = (float*)(ws + (6u << 20));                      // 64 KB
  unsigned short* wt      = (unsigned short*)(ws + (6u << 20) + (64u << 10)); // 40 KB

  prep_wt<<<(ODIM * KPAD + 255) / 256, 256, 0, stream>>>(W, wt);
  branch_mfma<true ><<<NGRP / 32, 256, 0, stream>>>(pos_feat, pos_w, wt, bias,
                                                    prelu_a, Ws, bs, pa_bf, pos_dot);
  branch_mfma<false><<<NGRP / 32, 256, 0, stream>>>(neg_feat, neg_w, wt, bias,
                                                    prelu_a, Ws, bs, np_bf, nullptr);
  score_kernel<<<dim3(NGRP / 256, JC), 256, 0, stream>>>(pa_bf, np_bf, partial);
  final_kernel<<<NGRP / 256, 256, 0, stream>>>(pos_dot, partial, (float*)d_out);
}